// Round 13
// baseline (400.544 us; speedup 1.0000x reference)
//
#include <hip/hip_runtime.h>

#define G 3
#define K 40
#define S 1024
#define NB 32
#define CH 30
#define T 16384
#define TP 4096
#define M 131072           // NB*TP
#define CT (CH*T)          // 491520
#define OUT_Q (NB*CH*T)    // 15728640
#define MARGIN 4e-3f

typedef __attribute__((ext_vector_type(8))) short short8;
typedef __attribute__((ext_vector_type(4))) float f32x4;

// ---- workspace layout ----
#define WS_LOSS 0
#define WS_E2   64                        // float[3][1024] = 12288
#define WS_P0   12352                     // short8[3*64*64] = 196608 each
#define WS_P1   208960
#define WS_P2   405568
#define WS_P3   602176

static __device__ __forceinline__ unsigned short f2bf(float f) {
    union { float f; unsigned int u; } v; v.f = f;
    unsigned int u = v.u;
    return (unsigned short)((u + 0x7fffu + ((u >> 16) & 1u)) >> 16);   // RNE
}
static __device__ __forceinline__ float bf2f(unsigned short h) {
    union { unsigned int u; float f; } v; v.u = ((unsigned int)h) << 16;
    return v.f;
}

// Slot map: kappa = 32*m + 8*lgrp + j over virtual K=128.
//   [0,40):  (eh, xh)   [40,80): (el, xh)   [80,120): (eh, xl)   [120,128): 0

// ================= prep: packed split fragments + e2 + loss zero (r11-proven) =================
__global__ void vq_prep_frag(const float* __restrict__ cb, short8* __restrict__ P0,
                             short8* __restrict__ P1, short8* __restrict__ P2,
                             short8* __restrict__ P3, float* __restrict__ e2,
                             double* __restrict__ loss) {
    int t = blockIdx.x * 256 + threadIdx.x;      // [0, 3*64*64)
    if (t == 0) *loss = 0.0;
    if (t >= G * 64 * 64) return;
    const int lane = t & 63;
    const int st   = (t >> 6) & 63;
    const int g    = t >> 12;
    const int lmod = lane & 15, lgrp = lane >> 4;
    const int s0   = st * 16;
    const float* cbg = cb + (size_t)g * S * K;

    if (lane < 16) {
        const float* row = cbg + (size_t)(s0 + lane) * K;
        float acc = 0.f;
        #pragma unroll
        for (int k = 0; k < K; ++k) acc = fmaf(row[k], row[k], acc);
        e2[g * S + s0 + lane] = -0.5f * acc;     // maximize D = x.e - 0.5||e||^2
    }

    const float* crow = cbg + (size_t)(s0 + lmod) * K;
    short8 P[4];
    #pragma unroll
    for (int m = 0; m < 4; ++m) {
        #pragma unroll
        for (int j = 0; j < 8; ++j) {
            int kap = 32 * m + 8 * lgrp + j;
            bool valid = kap < 120;
            int d = (kap < 40) ? kap : ((kap < 80) ? kap - 40 : kap - 80);
            float v = valid ? crow[d] : 0.f;
            unsigned short hh = f2bf(v);
            unsigned short ll = f2bf(v - bf2f(hh));
            bool low = (kap >= 40) && (kap < 80);
            P[m][j] = (short)(low ? ll : hh);
        }
    }
    const int slot = (g * 64 + st) * 64 + lane;
    P0[slot] = P[0]; P1[slot] = P[1]; P2[slot] = P[2]; P3[slot] = P[3];
}

// ==== main: 4-MFMA packed split, 4 s-tiles/barrier (16 iters), e2 in LDS ====
__global__ __launch_bounds__(256, 3) void vq_main_lds(
        const float* __restrict__ z, const float* __restrict__ cb,
        const short8* __restrict__ P0, const short8* __restrict__ P1,
        const short8* __restrict__ P2, const short8* __restrict__ P3,
        const float* __restrict__ e2, float* __restrict__ out,
        double* __restrict__ loss) {
    __shared__ short8 frag[2][4][4][64];        // [buf][sub][array][lane] = 32 KB
    __shared__ float  sE2[S];                   // 4 KB
    __shared__ float  sV1[4][64], sV2[4][64];
    __shared__ int    sIdx[4][64];
    __shared__ float  sXq[4][K];
    __shared__ double red[256];

    const int lane = threadIdx.x & 63;
    const int w    = threadIdx.x >> 6;
    const int g    = blockIdx.x >> 9;                     // 512 blocks per group
    const int qbase = ((blockIdx.x & 511) << 8) + (w << 6); // 64 queries per wave
    const int n    = qbase >> 12;
    const int tp0  = qbase & 4095;
    const int lmod = lane & 15, lgrp = lane >> 4;

    const float* zg  = z + (size_t)n * CT + (size_t)g * K * TP;
    const float* cbg = cb + (size_t)g * S * K;
    const float* e2g = e2 + g * S;

    // wave w stages packed array w for the whole block
    const short8* srcW = ((w == 0) ? P0 : (w == 1) ? P1 : (w == 2) ? P2 : P3)
                         + (size_t)g * 64 * 64;

    // ---- e2 into LDS once ----
    *(f32x4*)(sE2 + threadIdx.x * 4) = *(const f32x4*)(e2g + threadIdx.x * 4);

    // ---- x fragments (packed, B operand): xq[m][mt], same kappa map as prep ----
    short8 xq[4][4];
    #pragma unroll
    for (int mt = 0; mt < 4; ++mt) {
        int tp = tp0 + mt * 16 + lmod;
        #pragma unroll
        for (int m = 0; m < 4; ++m) {
            #pragma unroll
            for (int j = 0; j < 8; ++j) {
                int kap = 32 * m + 8 * lgrp + j;
                bool valid = kap < 120;
                int d = (kap < 40) ? kap : ((kap < 80) ? kap - 40 : kap - 80);
                float v = valid ? zg[(size_t)d * TP + tp] : 0.f;
                unsigned short hh = f2bf(v);
                unsigned short ll = f2bf(v - bf2f(hh));
                bool low = (kap >= 80) && (kap < 120);
                xq[m][mt][j] = (short)(low ? ll : hh);
            }
        }
    }

    float v1[4], v2[4]; int i1[4];
    #pragma unroll
    for (int mt = 0; mt < 4; ++mt) { v1[mt] = -3.4e38f; v2[mt] = -3.4e38f; i1[mt] = 0; }

    // ---- prologue: stage s-tiles 0..3 into buf 0 ----
    #pragma unroll
    for (int sub = 0; sub < 4; ++sub)
        frag[0][sub][w][lane] = srcW[sub * 64 + lane];
    __syncthreads();

    // ---- main loop: 16 iterations x 4 s-tiles, one barrier per iteration ----
    #pragma unroll 1
    for (int it = 0; it < 16; ++it) {
        const int cbuf = it & 1, nbuf = cbuf ^ 1;
        short8 nxt[4];
        if (it < 15) {
            #pragma unroll
            for (int sub = 0; sub < 4; ++sub)
                nxt[sub] = srcW[(4 * it + 4 + sub) * 64 + lane];   // issue early (VMEM)
        }

        #pragma unroll
        for (int sub = 0; sub < 4; ++sub) {
            const int st = 4 * it + sub;
            short8 p0 = frag[cbuf][sub][0][lane];
            short8 p1 = frag[cbuf][sub][1][lane];
            short8 p2 = frag[cbuf][sub][2][lane];
            short8 p3 = frag[cbuf][sub][3][lane];
            f32x4 e2v = *(const f32x4*)(sE2 + st * 16 + lgrp * 4);
            const int sbase = st * 16 + lgrp * 4;

            #pragma unroll
            for (int mt = 0; mt < 4; ++mt) {
                f32x4 d = __builtin_amdgcn_mfma_f32_16x16x32_bf16(p0, xq[0][mt], e2v, 0, 0, 0);
                d = __builtin_amdgcn_mfma_f32_16x16x32_bf16(p1, xq[1][mt], d, 0, 0, 0);
                d = __builtin_amdgcn_mfma_f32_16x16x32_bf16(p2, xq[2][mt], d, 0, 0, 0);
                d = __builtin_amdgcn_mfma_f32_16x16x32_bf16(p3, xq[3][mt], d, 0, 0, 0);
                #pragma unroll
                for (int j = 0; j < 4; ++j) {
                    float sj = d[j];
                    v2[mt] = __builtin_amdgcn_fmed3f(v1[mt], v2[mt], sj);  // 2nd-largest
                    bool cc = sj > v1[mt];
                    v1[mt] = fmaxf(v1[mt], sj);
                    i1[mt] = cc ? (sbase + j) : i1[mt];
                }
            }
        }

        if (it < 15) {
            #pragma unroll
            for (int sub = 0; sub < 4; ++sub)
                frag[nbuf][sub][w][lane] = nxt[sub];   // write-late (vmcnt drains here)
        }
        __syncthreads();
    }

    // ---- cross-lane merge (lanes m, m+16, m+32, m+48 share a query column) ----
    #pragma unroll
    for (int mt = 0; mt < 4; ++mt) {
        float a1 = v1[mt], a2 = v2[mt];
        int ii = i1[mt];
        #pragma unroll
        for (int off = 16; off < 64; off <<= 1) {
            float p1 = __shfl_xor(a1, off);
            float p2 = __shfl_xor(a2, off);
            int   pi = __shfl_xor(ii, off);
            float lo = fminf(a1, p1);
            a2 = fmaxf(fmaxf(a2, p2), lo);
            bool take = (p1 > a1) || (p1 == a1 && pi < ii);
            ii = take ? pi : ii;
            a1 = fmaxf(a1, p1);
        }
        if (lane < 16) {
            sV1[w][mt * 16 + lane] = a1;
            sV2[w][mt * 16 + lane] = a2;
            sIdx[w][mt * 16 + lane] = ii;
        }
    }
    __syncthreads();

    // ---- rare exact fp64 full rescan for near-tie queries (wave-cooperative) ----
    {
        bool need = (sV1[w][lane] - sV2[w][lane]) < MARGIN;
        unsigned long long mask = __ballot(need);
        while (mask) {
            int qq = __ffsll((unsigned long long)mask) - 1; mask &= mask - 1;
            int tpq = tp0 + qq;
            __threadfence_block();
            if (lane < K) sXq[w][lane] = zg[(size_t)lane * TP + tpq];
            __threadfence_block();
            double bestv = 1e300; int besti = 0;
            #pragma unroll 1
            for (int si = 0; si < 16; ++si) {
                int s = lane * 16 + si;
                const float* cr = cbg + (size_t)s * K;
                double acc = 0.0, en = 0.0;
                #pragma unroll 1
                for (int k = 0; k < K; ++k) {
                    double ev = (double)cr[k];
                    acc = fma(ev, (double)sXq[w][k], acc);
                    en  = fma(ev, ev, en);
                }
                double sc = 0.5 * en - acc;
                if (sc < bestv) { bestv = sc; besti = s; }
            }
            #pragma unroll
            for (int off = 1; off < 64; off <<= 1) {
                double pv = __shfl_xor(bestv, off);
                int    pi = __shfl_xor(besti, off);
                if (pv < bestv || (pv == bestv && pi < besti)) { bestv = pv; besti = pi; }
            }
            if (lane == 0) sIdx[w][qq] = besti;
        }
    }
    __syncthreads();

    // ---- gather winners -> output (coalesced), fp64 loss partials (group 2) ----
    double lsum = 0.0;
    {
        int tpq = tp0 + lane;
        int idx = sIdx[w][lane];
        const float* cr = cbg + (size_t)idx * K;
        float* op = out + (size_t)n * CT + (size_t)g * K * TP + tpq;
        #pragma unroll
        for (int k = 0; k < K; ++k) {
            float qv = cr[k];
            op[(size_t)k * TP] = qv;
            if (g == 2) {
                float xv = zg[(size_t)k * TP + tpq];
                double dd = (double)qv - (double)xv;
                lsum = fma(dd, dd, lsum);
            }
        }
    }

    if (g == 2) {
        red[threadIdx.x] = lsum;
        __syncthreads();
        for (int off = 128; off > 0; off >>= 1) {
            if (threadIdx.x < off) red[threadIdx.x] += red[threadIdx.x + off];
            __syncthreads();
        }
        if (threadIdx.x == 0) atomicAdd(loss, red[0]);
    }
}

// ---------------- finalize: scalar loss ----------------
__global__ void vq_fin_kernel(const double* __restrict__ loss, float* __restrict__ out) {
    out[OUT_Q] = (float)(0.25 * (*loss) / (double)((long long)M * K));
}

extern "C" void kernel_launch(void* const* d_in, const int* in_sizes, int n_in,
                              void* d_out, int out_size, void* d_ws, size_t ws_size,
                              hipStream_t stream) {
    const float* z  = (const float*)d_in[0];
    const float* cb = (const float*)d_in[1];
    float* out = (float*)d_out;

    char* ws = (char*)d_ws;
    double* loss = (double*)(ws + WS_LOSS);
    float*  e2   = (float*)(ws + WS_E2);
    short8* P0 = (short8*)(ws + WS_P0);
    short8* P1 = (short8*)(ws + WS_P1);
    short8* P2 = (short8*)(ws + WS_P2);
    short8* P3 = (short8*)(ws + WS_P3);

    vq_prep_frag<<<dim3(48), dim3(256), 0, stream>>>(cb, P0, P1, P2, P3, e2, loss);
    vq_main_lds<<<dim3(1536), dim3(256), 0, stream>>>(z, cb, P0, P1, P2, P3, e2, out, loss);
    vq_fin_kernel<<<dim3(1), dim3(1), 0, stream>>>(loss, out);
}

// Round 14
// 332.831 us; speedup vs baseline: 1.2034x; 1.2034x over previous
//
#include <hip/hip_runtime.h>

#define G 3
#define K 40
#define S 1024
#define NB 32
#define CH 30
#define T 16384
#define TP 4096
#define M 131072           // NB*TP
#define CT (CH*T)          // 491520
#define OUT_Q (NB*CH*T)    // 15728640
#define MARGIN 4e-3f

typedef __attribute__((ext_vector_type(8))) short short8;
typedef __attribute__((ext_vector_type(4))) float f32x4;

// ---- workspace layout ----
#define WS_LOSS 0
#define WS_E2   64                        // float[3][1024] = 12288
#define WS_P0   12352                     // short8[3*64*64] = 196608 each
#define WS_P1   208960
#define WS_P2   405568
#define WS_P3   602176

static __device__ __forceinline__ unsigned short f2bf(float f) {
    union { float f; unsigned int u; } v; v.f = f;
    unsigned int u = v.u;
    return (unsigned short)((u + 0x7fffu + ((u >> 16) & 1u)) >> 16);   // RNE
}
static __device__ __forceinline__ float bf2f(unsigned short h) {
    union { unsigned int u; float f; } v; v.u = ((unsigned int)h) << 16;
    return v.f;
}

// Slot map: kappa = 32*m + 8*lgrp + j over virtual K=128.
//   [0,40):  (eh, xh)   [40,80): (el, xh)   [80,120): (eh, xl)   [120,128): 0

// ================= prep: packed split fragments + e2 + loss zero (r11-proven) =================
__global__ void vq_prep_frag(const float* __restrict__ cb, short8* __restrict__ P0,
                             short8* __restrict__ P1, short8* __restrict__ P2,
                             short8* __restrict__ P3, float* __restrict__ e2,
                             double* __restrict__ loss) {
    int t = blockIdx.x * 256 + threadIdx.x;      // [0, 3*64*64)
    if (t == 0) *loss = 0.0;
    if (t >= G * 64 * 64) return;
    const int lane = t & 63;
    const int st   = (t >> 6) & 63;
    const int g    = t >> 12;
    const int lmod = lane & 15, lgrp = lane >> 4;
    const int s0   = st * 16;
    const float* cbg = cb + (size_t)g * S * K;

    if (lane < 16) {
        const float* row = cbg + (size_t)(s0 + lane) * K;
        float acc = 0.f;
        #pragma unroll
        for (int k = 0; k < K; ++k) acc = fmaf(row[k], row[k], acc);
        e2[g * S + s0 + lane] = -0.5f * acc;     // maximize D = x.e - 0.5||e||^2
    }

    const float* crow = cbg + (size_t)(s0 + lmod) * K;
    short8 P[4];
    #pragma unroll
    for (int m = 0; m < 4; ++m) {
        #pragma unroll
        for (int j = 0; j < 8; ++j) {
            int kap = 32 * m + 8 * lgrp + j;
            bool valid = kap < 120;
            int d = (kap < 40) ? kap : ((kap < 80) ? kap - 40 : kap - 80);
            float v = valid ? crow[d] : 0.f;
            unsigned short hh = f2bf(v);
            unsigned short ll = f2bf(v - bf2f(hh));
            bool low = (kap >= 40) && (kap < 80);
            P[m][j] = (short)(low ? ll : hh);
        }
    }
    const int slot = (g * 64 + st) * 64 + lane;
    P0[slot] = P[0]; P1[slot] = P[1]; P2[slot] = P[2]; P3[slot] = P[3];
}

// ==== main: r11 structure + depth-2 load pipeline (counted vmcnt) + e2 in LDS ====
__global__ __launch_bounds__(256, 3) void vq_main_lds(
        const float* __restrict__ z, const float* __restrict__ cb,
        const short8* __restrict__ P0, const short8* __restrict__ P1,
        const short8* __restrict__ P2, const short8* __restrict__ P3,
        const float* __restrict__ e2, float* __restrict__ out,
        double* __restrict__ loss) {
    __shared__ short8 frag[2][2][4][64];        // [buf][sub][array][lane] = 16 KB
    __shared__ float  sE2[S];                   // 4 KB
    __shared__ float  sV1[4][64], sV2[4][64];
    __shared__ int    sIdx[4][64];
    __shared__ float  sXq[4][K];
    __shared__ double red[256];

    const int lane = threadIdx.x & 63;
    const int w    = threadIdx.x >> 6;
    const int g    = blockIdx.x >> 9;                     // 512 blocks per group
    const int qbase = ((blockIdx.x & 511) << 8) + (w << 6); // 64 queries per wave
    const int n    = qbase >> 12;
    const int tp0  = qbase & 4095;
    const int lmod = lane & 15, lgrp = lane >> 4;

    const float* zg  = z + (size_t)n * CT + (size_t)g * K * TP;
    const float* cbg = cb + (size_t)g * S * K;
    const float* e2g = e2 + g * S;

    // wave w stages packed array w for the whole block
    const short8* srcW = ((w == 0) ? P0 : (w == 1) ? P1 : (w == 2) ? P2 : P3)
                         + (size_t)g * 64 * 64;

    // ---- e2 into LDS once ----
    *(f32x4*)(sE2 + threadIdx.x * 4) = *(const f32x4*)(e2g + threadIdx.x * 4);

    // ---- x fragments (packed, B operand): xq[m][mt], same kappa map as prep ----
    short8 xq[4][4];
    #pragma unroll
    for (int mt = 0; mt < 4; ++mt) {
        int tp = tp0 + mt * 16 + lmod;
        #pragma unroll
        for (int m = 0; m < 4; ++m) {
            #pragma unroll
            for (int j = 0; j < 8; ++j) {
                int kap = 32 * m + 8 * lgrp + j;
                bool valid = kap < 120;
                int d = (kap < 40) ? kap : ((kap < 80) ? kap - 40 : kap - 80);
                float v = valid ? zg[(size_t)d * TP + tp] : 0.f;
                unsigned short hh = f2bf(v);
                unsigned short ll = f2bf(v - bf2f(hh));
                bool low = (kap >= 80) && (kap < 120);
                xq[m][mt][j] = (short)(low ? ll : hh);
            }
        }
    }

    float v1[4], v2[4]; int i1[4];
    #pragma unroll
    for (int mt = 0; mt < 4; ++mt) { v1[mt] = -3.4e38f; v2[mt] = -3.4e38f; i1[mt] = 0; }

    // ---- prologue: stage pair 0 directly; preload pairs 1 (lda) and 2 (ifl) ----
    short8 lda0, lda1, if0, if1;
    {
        short8 c0 = srcW[lane];
        short8 c1 = srcW[64 + lane];
        frag[0][0][w][lane] = c0;
        frag[0][1][w][lane] = c1;
        lda0 = srcW[2 * 64 + lane];  lda1 = srcW[3 * 64 + lane];
        if0  = srcW[4 * 64 + lane];  if1  = srcW[5 * 64 + lane];
    }
    __syncthreads();

    // ---- main loop: 32 pair-iterations, depth-2 pipeline, one barrier/iter ----
    #pragma unroll 1
    for (int it = 0; it < 32; ++it) {
        const int cbuf = it & 1, nbuf = cbuf ^ 1;

        // write pair it+1 into the other buffer (counted vmcnt: ifl stays in flight)
        if (it < 31) {
            frag[nbuf][0][w][lane] = lda0;
            frag[nbuf][1][w][lane] = lda1;
        }

        // compute on buf[cbuf] = s-tiles 2it, 2it+1
        #pragma unroll
        for (int sub = 0; sub < 2; ++sub) {
            const int st = 2 * it + sub;
            short8 p0 = frag[cbuf][sub][0][lane];
            short8 p1 = frag[cbuf][sub][1][lane];
            short8 p2 = frag[cbuf][sub][2][lane];
            short8 p3 = frag[cbuf][sub][3][lane];
            f32x4 e2v = *(const f32x4*)(sE2 + st * 16 + lgrp * 4);
            const int sbase = st * 16 + lgrp * 4;

            #pragma unroll
            for (int mt = 0; mt < 4; ++mt) {
                f32x4 d = __builtin_amdgcn_mfma_f32_16x16x32_bf16(p0, xq[0][mt], e2v, 0, 0, 0);
                d = __builtin_amdgcn_mfma_f32_16x16x32_bf16(p1, xq[1][mt], d, 0, 0, 0);
                d = __builtin_amdgcn_mfma_f32_16x16x32_bf16(p2, xq[2][mt], d, 0, 0, 0);
                d = __builtin_amdgcn_mfma_f32_16x16x32_bf16(p3, xq[3][mt], d, 0, 0, 0);
                #pragma unroll
                for (int j = 0; j < 4; ++j) {
                    float sj = d[j];
                    v2[mt] = __builtin_amdgcn_fmed3f(v1[mt], v2[mt], sj);  // 2nd-largest
                    bool cc = sj > v1[mt];
                    v1[mt] = fmaxf(v1[mt], sj);
                    i1[mt] = cc ? (sbase + j) : i1[mt];
                }
            }
        }

        // rotate pipeline and issue pair it+3 (2 iterations of latency cover)
        lda0 = if0; lda1 = if1;
        {
            int p = (it + 3 < 32) ? (it + 3) : 0;
            if0 = srcW[(2 * p) * 64 + lane];
            if1 = srcW[(2 * p + 1) * 64 + lane];
        }
        __syncthreads();
    }

    // ---- cross-lane merge (lanes m, m+16, m+32, m+48 share a query column) ----
    #pragma unroll
    for (int mt = 0; mt < 4; ++mt) {
        float a1 = v1[mt], a2 = v2[mt];
        int ii = i1[mt];
        #pragma unroll
        for (int off = 16; off < 64; off <<= 1) {
            float p1 = __shfl_xor(a1, off);
            float p2 = __shfl_xor(a2, off);
            int   pi = __shfl_xor(ii, off);
            float lo = fminf(a1, p1);
            a2 = fmaxf(fmaxf(a2, p2), lo);
            bool take = (p1 > a1) || (p1 == a1 && pi < ii);
            ii = take ? pi : ii;
            a1 = fmaxf(a1, p1);
        }
        if (lane < 16) {
            sV1[w][mt * 16 + lane] = a1;
            sV2[w][mt * 16 + lane] = a2;
            sIdx[w][mt * 16 + lane] = ii;
        }
    }
    __syncthreads();

    // ---- rare exact fp64 full rescan for near-tie queries (wave-cooperative) ----
    {
        bool need = (sV1[w][lane] - sV2[w][lane]) < MARGIN;
        unsigned long long mask = __ballot(need);
        while (mask) {
            int qq = __ffsll((unsigned long long)mask) - 1; mask &= mask - 1;
            int tpq = tp0 + qq;
            __threadfence_block();
            if (lane < K) sXq[w][lane] = zg[(size_t)lane * TP + tpq];
            __threadfence_block();
            double bestv = 1e300; int besti = 0;
            #pragma unroll 1
            for (int si = 0; si < 16; ++si) {
                int s = lane * 16 + si;
                const float* cr = cbg + (size_t)s * K;
                double acc = 0.0, en = 0.0;
                #pragma unroll 1
                for (int k = 0; k < K; ++k) {
                    double ev = (double)cr[k];
                    acc = fma(ev, (double)sXq[w][k], acc);
                    en  = fma(ev, ev, en);
                }
                double sc = 0.5 * en - acc;
                if (sc < bestv) { bestv = sc; besti = s; }
            }
            #pragma unroll
            for (int off = 1; off < 64; off <<= 1) {
                double pv = __shfl_xor(bestv, off);
                int    pi = __shfl_xor(besti, off);
                if (pv < bestv || (pv == bestv && pi < besti)) { bestv = pv; besti = pi; }
            }
            if (lane == 0) sIdx[w][qq] = besti;
        }
    }
    __syncthreads();

    // ---- gather winners -> output (coalesced), fp64 loss partials (group 2) ----
    double lsum = 0.0;
    {
        int tpq = tp0 + lane;
        int idx = sIdx[w][lane];
        const float* cr = cbg + (size_t)idx * K;
        float* op = out + (size_t)n * CT + (size_t)g * K * TP + tpq;
        #pragma unroll
        for (int k = 0; k < K; ++k) {
            float qv = cr[k];
            op[(size_t)k * TP] = qv;
            if (g == 2) {
                float xv = zg[(size_t)k * TP + tpq];
                double dd = (double)qv - (double)xv;
                lsum = fma(dd, dd, lsum);
            }
        }
    }

    if (g == 2) {
        red[threadIdx.x] = lsum;
        __syncthreads();
        for (int off = 128; off > 0; off >>= 1) {
            if (threadIdx.x < off) red[threadIdx.x] += red[threadIdx.x + off];
            __syncthreads();
        }
        if (threadIdx.x == 0) atomicAdd(loss, red[0]);
    }
}

// ---------------- finalize: scalar loss ----------------
__global__ void vq_fin_kernel(const double* __restrict__ loss, float* __restrict__ out) {
    out[OUT_Q] = (float)(0.25 * (*loss) / (double)((long long)M * K));
}

extern "C" void kernel_launch(void* const* d_in, const int* in_sizes, int n_in,
                              void* d_out, int out_size, void* d_ws, size_t ws_size,
                              hipStream_t stream) {
    const float* z  = (const float*)d_in[0];
    const float* cb = (const float*)d_in[1];
    float* out = (float*)d_out;

    char* ws = (char*)d_ws;
    double* loss = (double*)(ws + WS_LOSS);
    float*  e2   = (float*)(ws + WS_E2);
    short8* P0 = (short8*)(ws + WS_P0);
    short8* P1 = (short8*)(ws + WS_P1);
    short8* P2 = (short8*)(ws + WS_P2);
    short8* P3 = (short8*)(ws + WS_P3);

    vq_prep_frag<<<dim3(48), dim3(256), 0, stream>>>(cb, P0, P1, P2, P3, e2, loss);
    vq_main_lds<<<dim3(1536), dim3(256), 0, stream>>>(z, cb, P0, P1, P2, P3, e2, out, loss);
    vq_fin_kernel<<<dim3(1), dim3(1), 0, stream>>>(loss, out);
}